// Round 5
// baseline (5113.686 us; speedup 1.0000x reference)
//
#include <hip/hip_runtime.h>
#include <math.h>

#define NTHR   1024
#define SWEEPS 7

// Ring movement (round-robin / Brent-Luk): content of slot s moves to next(s).
// slot 0 fixed; even s -> s+2 (62 -> 63); odd s -> s-2 (1 -> 2).
__device__ __forceinline__ int ring_next_even(int s) {   // s even
    return (s == 0) ? 0 : ((s == 62) ? 63 : s + 2);
}
__device__ __forceinline__ int ring_next_odd(int s) {    // s odd
    return (s == 1) ? 2 : s - 2;
}
// Split-parity column position: even cols -> 0..31, odd cols -> 32..63.
// 32 same-parity column accesses of one instr hit 32 distinct banks.
__device__ __forceinline__ int cpos(int c) {
    return (c >> 1) + ((c & 1) << 5);
}

// TWO matrices per block (tid 0..511 -> matrix 0, 512..1023 -> matrix 1).
// Barriers are block-wide, so each barrier pair now fences two matrix-rounds:
// per-matrix barrier/drain overhead halves while per-matrix LDS/VALU work and
// bank patterns are unchanged (16 KB matrix stride; each wave is entirely
// within one matrix). LDS 66,048 B -> 2 blocks/CU x 16 waves = 32 waves/CU.
//
// Within a matrix: symmetry-exploiting Jacobi round (A exactly symmetric).
// Each thread owns ONE unordered slot-pair block {p,q} (circular diagonal
// d = hw+1, p = k, q = (k+d)&31; d=1..15 full, d=16 half-masked -> 496 =
// C(32,2) blocks), reads it once, rotates once, writes block + transpose to
// ring-moved positions. Diagonal blocks closed-form by the 32 param threads.
__global__ __launch_bounds__(NTHR, 8)
void logeig_jacobi(const float* __restrict__ x, float* __restrict__ out) {
    __shared__ __align__(16) float  Ab[2 * 4096];   // slot rows x split-parity cols
    __shared__ __align__(16) float  Vb[2 * 4096];   // plain row-major
    __shared__ __align__(16) float2 pb[2 * 32];

    const int tid  = threadIdx.x;
    const int half = tid >> 9;             // which matrix
    const int t    = tid & 511;

    float*  A   = Ab + (half << 12);
    float*  Vt  = Vb + (half << 12);
    float2* prm = pb + (half << 5);

    const int k   = t & 31;                // p = k
    const int hw  = (t >> 5) & 15;         // half-wave 0..15
    const int d   = hw + 1;                // circular gap 1..16
    const int q   = (k + d) & 31;
    const bool act = (d < 16) || (k < 16); // d=16: only k<16 (avoid dup pairs)

    // A read offsets (thread-constant; slots never move for the reader)
    const int ro00 = (2 * k) * 64 + q;     // (+32, +64, +96 for the rest)

    // destinations after ring move
    const int dRp = ring_next_even(2 * k);
    const int dRq = ring_next_odd(2 * k + 1);
    const int dCp = cpos(ring_next_even(2 * q));
    const int dCq = cpos(ring_next_odd(2 * q + 1));
    const int tRp = ring_next_even(2 * q);
    const int tRq = ring_next_odd(2 * q + 1);
    const int tCp = cpos(ring_next_even(2 * k));
    const int tCq = cpos(ring_next_odd(2 * k + 1));

    const int w00 = dRp * 64 + dCp, w01 = dRp * 64 + dCq;
    const int w10 = dRq * 64 + dCp, w11 = dRq * 64 + dCq;
    const int u00 = tRp * 64 + tCp, u01 = tRp * 64 + tCq;  // <- n00, n10
    const int u10 = tRq * 64 + tCp, u11 = tRq * 64 + tCq;  // <- n01, n11
    // diag destinations (t < 32 only; p = k): rows dRp/dRq, cols tCp/tCq
    const int g00 = dRp * 64 + tCp, g01 = dRp * 64 + tCq;
    const int g10 = dRq * 64 + tCp, g11 = dRq * 64 + tCq;

    // Vt indices
    const int kv  = t >> 4;                // Vt row-pair id 0..31
    const int cch = t & 15;                // float4 chunk
    const int vdP = ring_next_even(2 * kv);
    const int vdQ = ring_next_odd(2 * kv + 1);

    const size_t base_el = ((size_t)blockIdx.x * 2 + half) * 4096;

    // ---- load A into split-parity layout (float4 -> two float2), Vt = I ----
    {
        const float4* x4 = (const float4*)(x + base_el);
        for (int idx4 = t; idx4 < 1024; idx4 += 512) {
            int i = idx4 >> 4, tt = idx4 & 15;     // cols 4tt..4tt+3
            float4 v = x4[idx4];
            *(float2*)&A[i * 64 + 2 * tt]      = make_float2(v.x, v.z);
            *(float2*)&A[i * 64 + 32 + 2 * tt] = make_float2(v.y, v.w);
            float4 id;
            id.x = (4 * tt + 0 == i) ? 1.0f : 0.0f;
            id.y = (4 * tt + 1 == i) ? 1.0f : 0.0f;
            id.z = (4 * tt + 2 == i) ? 1.0f : 0.0f;
            id.w = (4 * tt + 3 == i) ? 1.0f : 0.0f;
            *(float4*)&Vt[idx4 * 4] = id;
        }
    }
    __syncthreads();

    for (int sweep = 0; sweep < SWEEPS; ++sweep) {
        for (int r = 0; r < 63; ++r) {
            // ---- rotation params for the 32 adjacent slot pairs ----
            float app = 0.0f, apq = 0.0f, aqq = 0.0f, tpar = 0.0f;
            if (t < 32) {
                app = A[(2 * k) * 64 + k];            // pos(2k)   = k
                apq = A[(2 * k) * 64 + 32 + k];       // pos(2k+1) = 32+k
                aqq = A[(2 * k + 1) * 64 + 32 + k];
                float c = 1.0f, s = 0.0f;
                if (apq != 0.0f) {
                    float tau = (aqq - app) / (2.0f * apq);
                    tpar = copysignf(1.0f, tau) /
                           (fabsf(tau) + sqrtf(1.0f + tau * tau));
                    c = 1.0f / sqrtf(1.0f + tpar * tpar);
                    s = tpar * c;
                }
                prm[k] = make_float2(c, s);
            }

            // ---- read my 2x2 block (conflict-free b32) and Vt row-pair ----
            float m00 = 0.f, m01 = 0.f, m10 = 0.f, m11 = 0.f;
            if (act) {
                m00 = A[ro00];       m01 = A[ro00 + 32];
                m10 = A[ro00 + 64];  m11 = A[ro00 + 96];
            }
            float4 vtop = *(const float4*)&Vt[(2 * kv) * 64 + 4 * cch];
            float4 vbot = *(const float4*)&Vt[(2 * kv + 1) * 64 + 4 * cch];
            __syncthreads();   // B1: all reads done; prm visible

            float2 pV = prm[kv];           // 16-lane broadcast

            // ---- rotate block, write it + its transpose (ring-moved) ----
            if (act) {
                float2 pP = prm[k];
                float2 pQ = prm[q];
                float cP = pP.x, sP = pP.y, cQ = pQ.x, sQ = pQ.y;
                float t00 = cP * m00 - sP * m10, t01 = cP * m01 - sP * m11;
                float t10 = sP * m00 + cP * m10, t11 = sP * m01 + cP * m11;
                float n00 = cQ * t00 - sQ * t01, n01 = sQ * t00 + cQ * t01;
                float n10 = cQ * t10 - sQ * t11, n11 = sQ * t10 + cQ * t11;
                A[w00] = n00;  A[w01] = n01;
                A[w10] = n10;  A[w11] = n11;
                A[u00] = n00;  A[u01] = n10;   // transpose block
                A[u10] = n01;  A[u11] = n11;
            }
            // diagonal block: closed form, zero off-diagonals
            if (t < 32) {
                A[g00] = app - tpar * apq;
                A[g01] = 0.0f;
                A[g10] = 0.0f;
                A[g11] = aqq + tpar * apq;
            }

            // ---- rotate Vt row-pair, write to ring-moved rows ----
            {
                float cV = pV.x, sV = pV.y;
                float4 n0, n1;
                n0.x = cV * vtop.x - sV * vbot.x;  n1.x = sV * vtop.x + cV * vbot.x;
                n0.y = cV * vtop.y - sV * vbot.y;  n1.y = sV * vtop.y + cV * vbot.y;
                n0.z = cV * vtop.z - sV * vbot.z;  n1.z = sV * vtop.z + cV * vbot.z;
                n0.w = cV * vtop.w - sV * vbot.w;  n1.w = sV * vtop.w + cV * vbot.w;
                *(float4*)&Vt[vdP * 64 + 4 * cch] = n0;
                *(float4*)&Vt[vdQ * 64 + 4 * cch] = n1;
            }
            __syncthreads();   // B2: writes done -> next round
        }
    }

    // ---- epilogue: out = Vt^T diag(log diag A) Vt ----
    float* logw = (float*)prm;   // prm dead after sweeps; 64 floats = 32 float2
    if (t < 64) {
        int p = (t >> 1) + ((t & 1) << 5);   // cpos(t)
        logw[t] = logf(A[t * 64 + p]);
    }
    __syncthreads();

    // W[s][*] = Vt[s][*] * logw[s]  -> reuse A (plain layout now)
    for (int idx4 = t; idx4 < 1024; idx4 += 512) {
        int kk = idx4 >> 4;
        float lw = logw[kk];
        float4 v = *(const float4*)&Vt[idx4 * 4];
        v.x *= lw; v.y *= lw; v.z *= lw; v.w *= lw;
        *(float4*)&A[idx4 * 4] = v;
    }
    __syncthreads();

    // out[i][j] = sum_s W[s][i] * Vt[s][j]
    float4* out4 = (float4*)(out + base_el);
    for (int idx4 = t; idx4 < 1024; idx4 += 512) {
        int i = idx4 >> 4, j4 = idx4 & 15;
        float4 acc = make_float4(0.0f, 0.0f, 0.0f, 0.0f);
        #pragma unroll 8
        for (int kk = 0; kk < 64; ++kk) {
            float a = A[kk * 64 + i];
            float4 vv = *(const float4*)&Vt[kk * 64 + 4 * j4];
            acc.x += a * vv.x; acc.y += a * vv.y;
            acc.z += a * vv.z; acc.w += a * vv.w;
        }
        out4[idx4] = acc;
    }
}

extern "C" void kernel_launch(void* const* d_in, const int* in_sizes, int n_in,
                              void* d_out, int out_size, void* d_ws, size_t ws_size,
                              hipStream_t stream) {
    const float* x = (const float*)d_in[0];
    float* o = (float*)d_out;
    int B = in_sizes[0] / 4096;   // 8192
    logeig_jacobi<<<B / 2, NTHR, 0, stream>>>(x, o);
}

// Round 6
// 4720.760 us; speedup vs baseline: 1.0832x; 1.0832x over previous
//
#include <hip/hip_runtime.h>
#include <math.h>

#define NTHR   512
#define SWEEPS 7

// Ring movement (round-robin / Brent-Luk): content of slot s moves to next(s).
// slot 0 fixed; even s -> s+2 (62 -> 63); odd s -> s-2 (1 -> 2).
__device__ __forceinline__ int ring_next_even(int s) {   // s even
    return (s == 0) ? 0 : ((s == 62) ? 63 : s + 2);
}
__device__ __forceinline__ int ring_next_odd(int s) {    // s odd
    return (s == 1) ? 2 : s - 2;
}
// Inverse of the ring permutation over all 64 slots.
__device__ __forceinline__ int ring_prev(int s) {
    if (s == 0) return 0;
    if (s == 2) return 1;            // odd 1 -> 2
    if (!(s & 1)) return s - 2;      // even 4..62 <- s-2
    if (s == 63) return 62;          // even 62 -> 63
    return s + 2;                    // odd 1..61 <- s+2
}
// Split-parity column position: even cols -> 0..31, odd cols -> 32..63.
__device__ __forceinline__ int cpos(int c) {
    return (c >> 1) + ((c & 1) << 5);
}

// Symmetry-exploiting Jacobi with STAGED rotation parameters:
//   Round r+1's params depend only on values computed in round r:
//   new diagonals are closed-form (app - t*apq / aqq + t*apq), and the new
//   off-diagonal of next pair k' is one rotated n-element of the act thread
//   owning {k'-1, k'+1} (ring-inverse property; edge pairs {0,1} and {30,31}
//   handle k'=0,31). Those "stager" threads compute next-round c,s during the
//   WRITE phase (parallel to rotation VALU) into a double-buffered prm[2][32],
//   so the round's head is pure LDS loads -> B1: the serial
//   read->div/sqrt->write->barrier param chain is off the critical path.
__global__ __launch_bounds__(NTHR, 8)
void logeig_jacobi(const float* __restrict__ x, float* __restrict__ out) {
    __shared__ __align__(16) float  A[64 * 64];   // slot rows x split-parity cols
    __shared__ __align__(16) float  Vt[64 * 64];  // plain row-major
    __shared__ __align__(16) float2 prm[2][32];   // double-buffered params

    const int tid = threadIdx.x;
    const int k   = tid & 31;              // p = k
    const int hw  = tid >> 5;              // half-wave 0..15
    const int d   = hw + 1;                // circular gap 1..16
    const int q   = (k + d) & 31;
    const bool act = (d < 16) || (k < 16); // d=16: only k<16 (avoid dup pairs)

    // A read offsets (thread-constant; slots never move for the reader)
    const int ro00 = (2 * k) * 64 + q;     // (+32, +64, +96 for the rest)

    // destinations after ring move
    const int dRp = ring_next_even(2 * k);
    const int dRq = ring_next_odd(2 * k + 1);
    const int dCp = cpos(ring_next_even(2 * q));
    const int dCq = cpos(ring_next_odd(2 * q + 1));
    const int tRp = ring_next_even(2 * q);
    const int tRq = ring_next_odd(2 * q + 1);
    const int tCp = cpos(ring_next_even(2 * k));
    const int tCq = cpos(ring_next_odd(2 * k + 1));

    const int w00 = dRp * 64 + dCp, w01 = dRp * 64 + dCq;
    const int w10 = dRq * 64 + dCp, w11 = dRq * 64 + dCq;
    const int u00 = tRp * 64 + tCp, u01 = tRp * 64 + tCq;  // <- n00, n10
    const int u10 = tRq * 64 + tCp, u11 = tRq * 64 + tCq;  // <- n01, n11
    // diag destinations (t < 32 only; p = k): rows dRp/dRq, cols tCp/tCq
    const int g00 = dRp * 64 + tCp, g01 = dRp * 64 + tCq;
    const int g10 = dRq * 64 + tCp, g11 = dRq * 64 + tCq;

    // ---- stager assignment: next pair k' takes rows from old pairs
    // {ring_prev(2k')>>1, ring_prev(2k'+1)>>1} == {k'-1, k'+1} for k' in
    // [1,30] (d=2 threads k=k'-1), plus k'=0 <- {0,1} and k'=31 <- {30,31}.
    bool stg = false; int sk = 0;
    if (d == 1 && (k == 0 || k == 30)) { stg = true; sk = (k == 0) ? 0 : 31; }
    if (d == 2 && k <= 29)             { stg = true; sk = k + 1; }
    const int sa = ring_prev(2 * sk);        // old slot landing at 2k'  (pair k)
    const int sb = ring_prev(2 * sk + 1);    // old slot landing at 2k'+1 (pair q)
    const bool evenA = !(sa & 1);            // even row of pair k moved there?
    const bool evenB = !(sb & 1);
    const int  nsel  = ((sa & 1) << 1) | (sb & 1);   // which n is new apq

    // diag addresses of pairs k (=p) and q
    const int pa0 = (2 * k) * 64 + k;            // app(p)
    const int pa1 = (2 * k) * 64 + 32 + k;       // apq(p)
    const int pa2 = (2 * k + 1) * 64 + 32 + k;   // aqq(p)
    const int qa0 = (2 * q) * 64 + q;            // app(q)
    const int qa1 = (2 * q) * 64 + 32 + q;       // apq(q)
    const int qa2 = (2 * q + 1) * 64 + 32 + q;   // aqq(q)

    // Vt indices
    const int kv  = tid >> 4;              // Vt row-pair id 0..31
    const int cch = tid & 15;              // float4 chunk
    const int vdP = ring_next_even(2 * kv);
    const int vdQ = ring_next_odd(2 * kv + 1);

    const size_t base_el = (size_t)blockIdx.x * 4096;

    // ---- load A into split-parity layout (float4 -> two float2), Vt = I ----
    {
        const float4* x4 = (const float4*)(x + base_el);
        for (int idx4 = tid; idx4 < 1024; idx4 += NTHR) {
            int i = idx4 >> 4, t = idx4 & 15;      // cols 4t..4t+3
            float4 v = x4[idx4];
            *(float2*)&A[i * 64 + 2 * t]      = make_float2(v.x, v.z);
            *(float2*)&A[i * 64 + 32 + 2 * t] = make_float2(v.y, v.w);
            float4 id;
            id.x = (4 * t + 0 == i) ? 1.0f : 0.0f;
            id.y = (4 * t + 1 == i) ? 1.0f : 0.0f;
            id.z = (4 * t + 2 == i) ? 1.0f : 0.0f;
            id.w = (4 * t + 3 == i) ? 1.0f : 0.0f;
            ((float4*)Vt)[idx4] = id;
        }
    }
    __syncthreads();

    // ---- warm-up: params for round 0 (round 0's B1 fences the write) ----
    if (tid < 32) {
        float app = A[pa0], apq = A[pa1], aqq = A[pa2];
        float c = 1.0f, s = 0.0f;
        if (apq != 0.0f) {
            float tau = (aqq - app) / (2.0f * apq);
            float t   = copysignf(1.0f, tau) /
                        (fabsf(tau) + sqrtf(1.0f + tau * tau));
            c = 1.0f / sqrtf(1.0f + t * t);
            s = t * c;
        }
        prm[0][k] = make_float2(c, s);
    }

    int pi = 0;
    for (int sweep = 0; sweep < SWEEPS; ++sweep) {
        for (int r = 0; r < 63; ++r) {
            // ---- phase 1: pure loads (no param chain on the critical path) ----
            float m00 = 0.f, m01 = 0.f, m10 = 0.f, m11 = 0.f;
            if (act) {
                m00 = A[ro00];       m01 = A[ro00 + 32];
                m10 = A[ro00 + 64];  m11 = A[ro00 + 96];
            }
            float dg0 = 0.f, dg1 = 0.f, dg2 = 0.f;
            if (tid < 32) { dg0 = A[pa0]; dg1 = A[pa1]; dg2 = A[pa2]; }
            float sp0 = 0.f, sp1 = 0.f, sp2 = 0.f;
            float sq0 = 0.f, sq1 = 0.f, sq2 = 0.f;
            if (stg) {
                sp0 = A[pa0]; sp1 = A[pa1]; sp2 = A[pa2];
                sq0 = A[qa0]; sq1 = A[qa1]; sq2 = A[qa2];
            }
            float4 vtop = *(const float4*)&Vt[(2 * kv) * 64 + 4 * cch];
            float4 vbot = *(const float4*)&Vt[(2 * kv + 1) * 64 + 4 * cch];
            __syncthreads();   // B1: all reads done; prm[pi] visible

            const float2 pP = prm[pi][k];
            const float2 pQ = prm[pi][q];
            const float2 pV = prm[pi][kv];

            // ---- phase 2: rotate + writes + staged next-round params ----
            float n00 = 0.f, n01 = 0.f, n10 = 0.f, n11 = 0.f;
            if (act) {
                float cP = pP.x, sP = pP.y, cQ = pQ.x, sQ = pQ.y;
                float t00 = cP * m00 - sP * m10, t01 = cP * m01 - sP * m11;
                float t10 = sP * m00 + cP * m10, t11 = sP * m01 + cP * m11;
                n00 = cQ * t00 - sQ * t01;  n01 = sQ * t00 + cQ * t01;
                n10 = cQ * t10 - sQ * t11;  n11 = sQ * t10 + cQ * t11;
                A[w00] = n00;  A[w01] = n01;
                A[w10] = n10;  A[w11] = n11;
                A[u00] = n00;  A[u01] = n10;   // transpose block
                A[u10] = n01;  A[u11] = n11;
            }
            // diagonal block of pair k: closed form via tpar = s/c
            if (tid < 32) {
                float tpar = pP.y / pP.x;      // c >= 1/sqrt(2), safe
                A[g00] = dg0 - tpar * dg1;
                A[g01] = 0.0f;
                A[g10] = 0.0f;
                A[g11] = dg2 + tpar * dg1;
            }
            // stage params for next round's pair sk
            if (stg) {
                float tp = pP.y / pP.x;
                float tq = pQ.y / pQ.x;
                float diagA = evenA ? (sp0 - tp * sp1) : (sp2 + tp * sp1);
                float diagB = evenB ? (sq0 - tq * sq1) : (sq2 + tq * sq1);
                float napq  = (nsel == 0) ? n00 : (nsel == 1) ? n01
                            : (nsel == 2) ? n10 : n11;
                float c = 1.0f, s = 0.0f;
                if (napq != 0.0f) {
                    float tau = (diagB - diagA) / (2.0f * napq);
                    float t   = copysignf(1.0f, tau) /
                                (fabsf(tau) + sqrtf(1.0f + tau * tau));
                    c = 1.0f / sqrtf(1.0f + t * t);
                    s = t * c;
                }
                prm[pi ^ 1][sk] = make_float2(c, s);
            }

            // ---- rotate Vt row-pair, write to ring-moved rows ----
            {
                float cV = pV.x, sV = pV.y;
                float4 n0, n1;
                n0.x = cV * vtop.x - sV * vbot.x;  n1.x = sV * vtop.x + cV * vbot.x;
                n0.y = cV * vtop.y - sV * vbot.y;  n1.y = sV * vtop.y + cV * vbot.y;
                n0.z = cV * vtop.z - sV * vbot.z;  n1.z = sV * vtop.z + cV * vbot.z;
                n0.w = cV * vtop.w - sV * vbot.w;  n1.w = sV * vtop.w + cV * vbot.w;
                *(float4*)&Vt[vdP * 64 + 4 * cch] = n0;
                *(float4*)&Vt[vdQ * 64 + 4 * cch] = n1;
            }
            pi ^= 1;
            __syncthreads();   // B2: writes done -> next round
        }
    }

    // ---- epilogue: out = Vt^T diag(log diag A) Vt ----
    float* logw = (float*)prm;   // prm dead after sweeps; 64 floats fit in 512B
    if (tid < 64) {
        int p = (tid >> 1) + ((tid & 1) << 5);   // cpos(tid)
        logw[tid] = logf(A[tid * 64 + p]);
    }
    __syncthreads();

    // W[s][*] = Vt[s][*] * logw[s]  -> reuse A (plain layout now)
    for (int idx4 = tid; idx4 < 1024; idx4 += NTHR) {
        int kk = idx4 >> 4;
        float lw = logw[kk];
        float4 v = ((float4*)Vt)[idx4];
        v.x *= lw; v.y *= lw; v.z *= lw; v.w *= lw;
        ((float4*)A)[idx4] = v;
    }
    __syncthreads();

    // out[i][j] = sum_s W[s][i] * Vt[s][j]
    float4* out4 = (float4*)(out + base_el);
    for (int idx4 = tid; idx4 < 1024; idx4 += NTHR) {
        int i = idx4 >> 4, j4 = idx4 & 15;
        float4 acc = make_float4(0.0f, 0.0f, 0.0f, 0.0f);
        #pragma unroll 8
        for (int kk = 0; kk < 64; ++kk) {
            float a = A[kk * 64 + i];
            float4 vv = ((float4*)Vt)[kk * 16 + j4];
            acc.x += a * vv.x; acc.y += a * vv.y;
            acc.z += a * vv.z; acc.w += a * vv.w;
        }
        out4[idx4] = acc;
    }
}

extern "C" void kernel_launch(void* const* d_in, const int* in_sizes, int n_in,
                              void* d_out, int out_size, void* d_ws, size_t ws_size,
                              hipStream_t stream) {
    const float* x = (const float*)d_in[0];
    float* o = (float*)d_out;
    int B = in_sizes[0] / 4096;   // 8192
    logeig_jacobi<<<B, NTHR, 0, stream>>>(x, o);
}

// Round 7
// 4164.654 us; speedup vs baseline: 1.2279x; 1.1335x over previous
//
#include <hip/hip_runtime.h>
#include <math.h>

#define NTHR   512
#define SWEEPS 7

// Ring movement (round-robin / Brent-Luk): content of slot s moves to next(s).
// slot 0 fixed; even s -> s+2 (62 -> 63); odd s -> s-2 (1 -> 2).
__device__ __forceinline__ int ring_next_even(int s) {   // s even
    return (s == 0) ? 0 : ((s == 62) ? 63 : s + 2);
}
__device__ __forceinline__ int ring_next_odd(int s) {    // s odd
    return (s == 1) ? 2 : s - 2;
}
// Split-parity column position: even cols -> 0..31, odd cols -> 32..63.
// 32 same-parity column accesses of one instr hit 32 distinct banks.
__device__ __forceinline__ int cpos(int c) {
    return (c >> 1) + ((c & 1) << 5);
}
// Canonical (upper-triangle, pair-ordered) storage address of element (R,C):
// store at (R,C) if pair(R)<pair(C), or same pair with R<=C; else transpose.
__device__ __forceinline__ int canon(int R, int C) {
    int pi = R >> 1, pj = C >> 1;
    bool sw = (pi > pj) || (pi == pj && R > C);
    int r = sw ? C : R;
    int c = sw ? R : C;
    return r * 64 + cpos(c);
}

// Symmetry-exploiting Jacobi, CANONICAL-ONLY A storage:
//   A is exactly symmetric, so only the pair-ordered orientation of each 2x2
//   block is stored. Each act thread owns one unordered pair {p,q} (circular
//   diagonal d = hw+1; 496 = C(32,2) blocks), reads the canonical block
//   (transposed offsets if k>q, thread-constant), rotates once, and writes
//   FOUR canonical elements (was 8 with the mirror copy). Diagonal blocks:
//   closed form, 2 diag values + 1 canonical zero (was 4). This halves A's
//   LDS write traffic; the remaining LDS cost is dominated by Vt's b128
//   bandwidth floor (the invariant 4.6e8 "conflict" cycles).
__global__ __launch_bounds__(NTHR, 8)
void logeig_jacobi(const float* __restrict__ x, float* __restrict__ out) {
    __shared__ __align__(16) float  A[64 * 64];   // slot rows x split-parity cols
    __shared__ __align__(16) float  Vt[64 * 64];  // plain row-major
    __shared__ __align__(16) float2 prm[32];
    __shared__ float logw[64];

    const int tid = threadIdx.x;
    const int k   = tid & 31;              // own pair
    const int hw  = tid >> 5;              // half-wave 0..15
    const int d   = hw + 1;                // circular gap 1..16
    const int q   = (k + d) & 31;          // partner pair
    const bool act = (d < 16) || (k < 16); // d=16: only k<16 (avoid dup pairs)

    // ---- canonical READ offsets (thread-constant) ----
    // stored block S = (rows of pair bi) x (cols of pair bj), bi<=bj;
    // my M (rows = pair k, cols = pair q) = flip ? S^T : S.
    const bool flip = (k > q);
    const int bi = flip ? q : k, bj = flip ? k : q;
    const int rbase = (2 * bi) * 64 + bj;       // S00: cpos(2bj)=bj
    const int r00 = rbase;                      // m00 = S00
    const int r01 = flip ? (rbase + 64) : (rbase + 32);   // m01 = flip?S10:S01
    const int r10 = flip ? (rbase + 32) : (rbase + 64);   // m10 = flip?S01:S10
    const int r11 = rbase + 96;                 // m11 = S11

    // ---- canonical WRITE addresses after ring move ----
    const int R0 = ring_next_even(2 * k), R1 = ring_next_odd(2 * k + 1);
    const int C0 = ring_next_even(2 * q), C1 = ring_next_odd(2 * q + 1);
    const int a00 = canon(R0, C0), a01 = canon(R0, C1);
    const int a10 = canon(R1, C0), a11 = canon(R1, C1);
    // diag-block destinations (tid < 32): two diagonals + one canonical zero
    const int gd0 = R0 * 64 + cpos(R0);
    const int gd1 = R1 * 64 + cpos(R1);
    const int gz  = canon(R0, R1);

    // Vt indices (unchanged)
    const int kv  = tid >> 4;              // Vt row-pair id 0..31
    const int cch = tid & 15;              // float4 chunk
    const int vdP = ring_next_even(2 * kv);
    const int vdQ = ring_next_odd(2 * kv + 1);

    const size_t base_el = (size_t)blockIdx.x * 4096;

    // ---- load A into split-parity layout (float4 -> two float2), Vt = I ----
    {
        const float4* x4 = (const float4*)(x + base_el);
        for (int idx4 = tid; idx4 < 1024; idx4 += NTHR) {
            int i = idx4 >> 4, t = idx4 & 15;      // cols 4t..4t+3
            float4 v = x4[idx4];
            *(float2*)&A[i * 64 + 2 * t]      = make_float2(v.x, v.z);
            *(float2*)&A[i * 64 + 32 + 2 * t] = make_float2(v.y, v.w);
            float4 id;
            id.x = (4 * t + 0 == i) ? 1.0f : 0.0f;
            id.y = (4 * t + 1 == i) ? 1.0f : 0.0f;
            id.z = (4 * t + 2 == i) ? 1.0f : 0.0f;
            id.w = (4 * t + 3 == i) ? 1.0f : 0.0f;
            ((float4*)Vt)[idx4] = id;
        }
    }
    __syncthreads();

    for (int sweep = 0; sweep < SWEEPS; ++sweep) {
        for (int r = 0; r < 63; ++r) {
            // ---- rotation params for the 32 adjacent slot pairs ----
            float app = 0.0f, apq = 0.0f, aqq = 0.0f, tpar = 0.0f;
            if (tid < 32) {
                app = A[(2 * k) * 64 + k];            // (2k,2k)
                apq = A[(2 * k) * 64 + 32 + k];       // (2k,2k+1) canonical
                aqq = A[(2 * k + 1) * 64 + 32 + k];   // (2k+1,2k+1)
                float c = 1.0f, s = 0.0f;
                if (apq != 0.0f) {
                    float tau = (aqq - app) / (2.0f * apq);
                    tpar = copysignf(1.0f, tau) /
                           (fabsf(tau) + sqrtf(1.0f + tau * tau));
                    c = 1.0f / sqrtf(1.0f + tpar * tpar);
                    s = tpar * c;
                }
                prm[k] = make_float2(c, s);
            }

            // ---- read canonical 2x2 block (b32, <=2-way) and Vt row-pair ----
            float m00 = 0.f, m01 = 0.f, m10 = 0.f, m11 = 0.f;
            if (act) {
                m00 = A[r00];  m01 = A[r01];
                m10 = A[r10];  m11 = A[r11];
            }
            float4 vtop = *(const float4*)&Vt[(2 * kv) * 64 + 4 * cch];
            float4 vbot = *(const float4*)&Vt[(2 * kv + 1) * 64 + 4 * cch];
            __syncthreads();   // B1: all reads done; prm visible

            float2 pV = prm[kv];           // 16-lane broadcast

            // ---- rotate block, write 4 canonical elements ----
            if (act) {
                float2 pP = prm[k];
                float2 pQ = prm[q];
                float cP = pP.x, sP = pP.y, cQ = pQ.x, sQ = pQ.y;
                float t00 = cP * m00 - sP * m10, t01 = cP * m01 - sP * m11;
                float t10 = sP * m00 + cP * m10, t11 = sP * m01 + cP * m11;
                float n00 = cQ * t00 - sQ * t01, n01 = sQ * t00 + cQ * t01;
                float n10 = cQ * t10 - sQ * t11, n11 = sQ * t10 + cQ * t11;
                A[a00] = n00;  A[a01] = n01;
                A[a10] = n10;  A[a11] = n11;
            }
            // diagonal block: closed form; one canonical zero
            if (tid < 32) {
                A[gd0] = app - tpar * apq;
                A[gd1] = aqq + tpar * apq;
                A[gz]  = 0.0f;
            }

            // ---- rotate Vt row-pair, write to ring-moved rows ----
            {
                float cV = pV.x, sV = pV.y;
                float4 n0, n1;
                n0.x = cV * vtop.x - sV * vbot.x;  n1.x = sV * vtop.x + cV * vbot.x;
                n0.y = cV * vtop.y - sV * vbot.y;  n1.y = sV * vtop.y + cV * vbot.y;
                n0.z = cV * vtop.z - sV * vbot.z;  n1.z = sV * vtop.z + cV * vbot.z;
                n0.w = cV * vtop.w - sV * vbot.w;  n1.w = sV * vtop.w + cV * vbot.w;
                *(float4*)&Vt[vdP * 64 + 4 * cch] = n0;
                *(float4*)&Vt[vdQ * 64 + 4 * cch] = n1;
            }
            __syncthreads();   // B2: writes done -> next round
        }
    }

    // ---- epilogue: out = Vt^T diag(log diag A) Vt ----
    if (tid < 64) {
        int p = (tid >> 1) + ((tid & 1) << 5);   // cpos(tid) — diag is canonical
        logw[tid] = logf(A[tid * 64 + p]);
    }
    __syncthreads();

    // W[s][*] = Vt[s][*] * logw[s]  -> reuse A (plain layout now)
    for (int idx4 = tid; idx4 < 1024; idx4 += NTHR) {
        int kk = idx4 >> 4;
        float lw = logw[kk];
        float4 v = ((float4*)Vt)[idx4];
        v.x *= lw; v.y *= lw; v.z *= lw; v.w *= lw;
        ((float4*)A)[idx4] = v;
    }
    __syncthreads();

    // out[i][j] = sum_s W[s][i] * Vt[s][j]
    float4* out4 = (float4*)(out + base_el);
    for (int idx4 = tid; idx4 < 1024; idx4 += NTHR) {
        int i = idx4 >> 4, j4 = idx4 & 15;
        float4 acc = make_float4(0.0f, 0.0f, 0.0f, 0.0f);
        #pragma unroll 8
        for (int kk = 0; kk < 64; ++kk) {
            float a = A[kk * 64 + i];
            float4 vv = ((float4*)Vt)[kk * 16 + j4];
            acc.x += a * vv.x; acc.y += a * vv.y;
            acc.z += a * vv.z; acc.w += a * vv.w;
        }
        out4[idx4] = acc;
    }
}

extern "C" void kernel_launch(void* const* d_in, const int* in_sizes, int n_in,
                              void* d_out, int out_size, void* d_ws, size_t ws_size,
                              hipStream_t stream) {
    const float* x = (const float*)d_in[0];
    float* o = (float*)d_out;
    int B = in_sizes[0] / 4096;   // 8192
    logeig_jacobi<<<B, NTHR, 0, stream>>>(x, o);
}